// Round 13
// baseline (110.361 us; speedup 1.0000x reference)
//
#include <hip/hip_runtime.h>
#include <hip/hip_bf16.h>
#include <stdint.h>

typedef __bf16 bf16;
typedef __bf16 bf16x8 __attribute__((ext_vector_type(8)));
typedef float f32x16 __attribute__((ext_vector_type(16)));

#define GAS __attribute__((address_space(1)))
#define LAS __attribute__((address_space(3)))

static constexpr int M = 4096;   // batch
static constexpr int N = 2048;   // 2C
static constexpr int K = 2048;   // 2C

// ---- G3 geometry: 128x256, 8 waves (2M x 4N, 64x64/wave), 32x32x16 MFMA ----
static constexpr int BM = 128, BN = 256, BK = 64;
static constexpr int NT = K / BK;               // 32 K-tiles
static constexpr int A_ELE = BM * BK;           // 16 KB
static constexpr int B_ELE = BN * BK;           // 32 KB
static constexpr int BUF_ELE = A_ELE + B_ELE;   // 48 KB; x3 = 144 KB

// ---- G1/G2 geometry: 64x128, 4 waves (2M x 2N, 32x64/wave), 2 blocks/CU ----
static constexpr int WA_ELE = 64 * BK;              // 8 KB
static constexpr int WB_ELE = 128 * BK;             // 16 KB
static constexpr int WBUF_ELE = WA_ELE + WB_ELE;    // 24 KB; x3 = 72 KB
static constexpr int WGRID = 512;

// --- async global->LDS, 16B per lane, dest = wave-uniform base + lane*16 ---
__device__ __forceinline__ void gload_lds16(const bf16* gsrc, bf16* ldst) {
    __builtin_amdgcn_global_load_lds((const GAS void*)gsrc, (LAS void*)ldst, 16, 0, 0);
}

// ---- pack 8 fp32 -> 8 bf16 ----
__device__ __forceinline__ void pack8(const float* __restrict__ src, bf16* __restrict__ dst) {
    float4 v0 = *reinterpret_cast<const float4*>(src);
    float4 v1 = *reinterpret_cast<const float4*>(src + 4);
    bf16x8 o;
    o[0] = (bf16)v0.x; o[1] = (bf16)v0.y; o[2] = (bf16)v0.z; o[3] = (bf16)v0.w;
    o[4] = (bf16)v1.x; o[5] = (bf16)v1.y; o[6] = (bf16)v1.z; o[7] = (bf16)v1.w;
    *reinterpret_cast<bf16x8*>(dst) = o;
}

// ---- 32x32 LDS-tiled transpose: Wt[n][k] = (bf16)W[k][n] ----
__device__ __forceinline__ void transpose_tile(const float* __restrict__ W, bf16* __restrict__ Wt,
                                               int t, int tid, bf16 (*tile)[33]) {
    int n0 = (t & 63) * 32;
    int k0 = (t >> 6) * 32;
    int tx = tid & 31;
    int ty = tid >> 5;
    #pragma unroll
    for (int i = 0; i < 4; i++) {
        int k = ty + i * 8;
        tile[k][tx] = (bf16)W[(size_t)(k0 + k) * N + n0 + tx];
    }
    __syncthreads();
    #pragma unroll
    for (int i = 0; i < 4; i++) {
        int n = ty + i * 8;
        Wt[(size_t)(n0 + n) * K + k0 + tx] = tile[tx][n];
    }
}

// ================= weight GEMM body (64x128 tile, 4 waves, 32x32x16) =================
__device__ __forceinline__ void gemmw_body(const bf16* __restrict__ A,
                                           const bf16* __restrict__ Bt,
                                           bf16* __restrict__ C,
                                           int bid, bf16* lds) {
    int swz = (bid & 7) * (WGRID >> 3) + (bid >> 3);
    int tm = swz >> 4;
    int tn = swz & 15;

    int tid  = threadIdx.x;
    int wave = tid >> 6;
    int lane = tid & 63;
    int wr = wave >> 1;          // M half (32 rows)
    int wc = wave & 1;           // N half (64 cols)
    int fr5 = lane & 31;
    int hi  = lane >> 5;

    int srow = tid >> 3;
    int scol = ((tid & 7) ^ (srow & 7)) * 8;
    const bf16* aS = A  + (size_t)(tm * 64  + srow) * K + scol;
    const bf16* bS = Bt + (size_t)(tn * 128 + srow) * K + scol;
    int sdst = wave * 512;

    // frag geometry: row = base + fr5 (row&7 == fr5&7); 16B slot s = kf*2+hi, read (s^(fr5&7))
    int aoff = (wr * 32 + fr5) * 64;
    int boff = (wc * 64 + fr5) * 64;
    int sw   = fr5 & 7;
    int sl[4];
    #pragma unroll
    for (int kf = 0; kf < 4; kf++) sl[kf] = ((((kf << 1) | hi)) ^ sw) * 8;

    f32x16 acc[2] = {};                                    // (ni) — 1 m-frag x 2 n-frags
    bf16x8 av[4], bv[2][4];

    auto STAGE = [&](int bi, int t) {
        bf16* ba = lds + bi * WBUF_ELE;
        bf16* bb = ba + WA_ELE;
        const bf16* a = aS + t * BK;
        const bf16* b = bS + t * BK;
        gload_lds16(a,          ba + sdst);
        gload_lds16(a + 32 * K, ba + sdst + 2048);
        #pragma unroll
        for (int c = 0; c < 4; c++)
            gload_lds16(b + (size_t)c * 32 * K, bb + sdst + c * 2048);
    };
    auto READ = [&](const bf16* buf) {                     // 12 ds_read_b128
        const bf16* ba = buf;
        const bf16* bb = buf + WA_ELE;
        #pragma unroll
        for (int kf = 0; kf < 4; kf++)
            av[kf] = *reinterpret_cast<const bf16x8*>(ba + aoff + sl[kf]);
        #pragma unroll
        for (int ni = 0; ni < 2; ni++)
            #pragma unroll
            for (int kf = 0; kf < 4; kf++)
                bv[ni][kf] = *reinterpret_cast<const bf16x8*>(bb + boff + ni * 2048 + sl[kf]);
    };
    auto MFMA8 = [&]() {
        #pragma unroll
        for (int kf = 0; kf < 4; kf++)
            #pragma unroll
            for (int ni = 0; ni < 2; ni++)
                acc[ni] = __builtin_amdgcn_mfma_f32_32x32x16_bf16(av[kf], bv[ni][kf], acc[ni], 0, 0, 0);
    };
    auto TILE = [&](int t, int cb, int sb) {
        READ(lds + cb * WBUF_ELE);
        STAGE(sb, t + 2);
        __builtin_amdgcn_s_setprio(1);
        MFMA8();
        __builtin_amdgcn_s_setprio(0);
        asm volatile("s_waitcnt lgkmcnt(0)" ::: "memory");
        asm volatile("s_waitcnt vmcnt(6)" ::: "memory");
        __builtin_amdgcn_s_barrier();
    };

    STAGE(0, 0);
    STAGE(1, 1);
    asm volatile("s_waitcnt vmcnt(6)" ::: "memory");
    __builtin_amdgcn_s_barrier();

    for (int i = 0; i < 10; ++i) {
        TILE(3 * i,     0, 2);
        TILE(3 * i + 1, 1, 0);
        TILE(3 * i + 2, 2, 1);
    }
    {
        READ(lds);
        MFMA8();
        asm volatile("s_waitcnt lgkmcnt(0)" ::: "memory");
        asm volatile("s_waitcnt vmcnt(0)" ::: "memory");
        __builtin_amdgcn_s_barrier();
    }
    {
        READ(lds + WBUF_ELE);
        MFMA8();
    }

    // C/D layout (32x32): col = lane&31, row = (reg&3) + 8*(reg>>2) + 4*(lane>>5)
    int row0 = tm * 64 + wr * 32 + 4 * hi;
    int col0 = tn * 128 + wc * 64 + fr5;
    #pragma unroll
    for (int ni = 0; ni < 2; ni++)
        #pragma unroll
        for (int r = 0; r < 16; r++) {
            int row = row0 + (r & 3) + 8 * (r >> 2);
            C[(size_t)row * 2048 + col0 + ni * 32] = (bf16)acc[ni][r];
        }
}

// ===== K1: pack W0 ; transpose W1 =====
__global__ __launch_bounds__(256) void k1_prep(const float* __restrict__ W0, bf16* __restrict__ W0pk,
                                               const float* __restrict__ W1, bf16* __restrict__ W1t) {
    __shared__ bf16 tile[32][33];
    int bid = blockIdx.x;
    int tid = threadIdx.x;
    if (bid < 2048) {
        int idx = (bid * 256 + tid) * 8;
        pack8(W0 + idx, W0pk + idx);
    } else {
        transpose_tile(W1, W1t, bid - 2048, tid, tile);
    }
}

// ===== K2: G1 || transpose W2 =====
__global__ __launch_bounds__(256, 2) void g1_fused(const bf16* __restrict__ A, const bf16* __restrict__ Bt,
                                                   bf16* __restrict__ C,
                                                   const float* __restrict__ W2, bf16* __restrict__ W2t) {
    __shared__ bf16 lds[3 * WBUF_ELE];
    int bid = blockIdx.x;
    if (bid < WGRID) {
        gemmw_body(A, Bt, C, bid, lds);
    } else {
        transpose_tile(W2, W2t, bid - WGRID, threadIdx.x, (bf16(*)[33])lds);
    }
}

// ===== K3: G2 || pack X =====
__global__ __launch_bounds__(256, 2) void g2_fused(const bf16* __restrict__ A, const bf16* __restrict__ Bt,
                                                   bf16* __restrict__ C,
                                                   const float* __restrict__ x0, const float* __restrict__ x1,
                                                   bf16* __restrict__ Xpk) {
    __shared__ bf16 lds[3 * WBUF_ELE];
    int bid = blockIdx.x;
    if (bid < WGRID) {
        gemmw_body(A, Bt, C, bid, lds);
    } else {
        int idx = ((bid - WGRID) * 256 + threadIdx.x) * 8;
        int b = idx >> 11;
        int c = idx & 2047;
        const float* src = (c < 1024) ? (x0 + (size_t)b * 1024 + c)
                                      : (x1 + (size_t)b * 1024 + (c - 1024));
        pack8(src, Xpk + idx);
    }
}

// ========== K4: G3 = Xpk @ W012t^T (128x256, 8 waves, 32x32x16 MFMA) ==========
__global__ __launch_bounds__(512, 2) void gemmx_kernel(const bf16* __restrict__ A,   // [4096][K]
                                                       const bf16* __restrict__ Bt,  // [N][K]
                                                       float* __restrict__ Cout) {   // [4096][N] fp32
    __shared__ bf16 lds[3 * BUF_ELE];   // 144 KB

    int bid = blockIdx.x;
    int cpx = gridDim.x >> 3;
    int swz = (bid & 7) * cpx + (bid >> 3);
    int tm = swz >> 3;                           // 0..31
    int tn = swz & 7;                            // 0..7

    int tid  = threadIdx.x;
    int wave = tid >> 6;
    int lane = tid & 63;
    int wr = wave >> 2;          // M half (64 rows)
    int wc = wave & 3;           // N quarter (64 cols)
    int fr5 = lane & 31;
    int hi  = lane >> 5;

    int srow = wave * 8 + (lane >> 3);
    int scol = ((lane & 7) ^ (lane >> 3)) * 8;            // T2 pre-swizzle
    const bf16* aS = A  + (size_t)(tm * BM + srow) * K + scol;
    const bf16* bS = Bt + (size_t)(tn * BN + srow) * K + scol;
    int sdst = wave * 512;

    // frag geometry: row = base + mi*32 + fr5 (bases are mult of 32 -> row&7 == fr5&7)
    int aoff = (wr * 64 + fr5) * 64;
    int boff = (wc * 64 + fr5) * 64;
    int sw   = fr5 & 7;
    int sl[4];
    #pragma unroll
    for (int kf = 0; kf < 4; kf++) sl[kf] = ((((kf << 1) | hi)) ^ sw) * 8;

    f32x16 acc[2][2] = {};                                 // (mi, ni)
    bf16x8 av[2][4], bv[2][4];

    auto STAGE = [&](int bi, int t) {
        bf16* ba = (bf16*)lds + bi * BUF_ELE;
        bf16* bb = ba + A_ELE;
        const bf16* a = aS + t * BK;
        const bf16* b = bS + t * BK;
        gload_lds16(a,           ba + sdst);
        gload_lds16(a + 64 * K,  ba + sdst + 4096);
        gload_lds16(b,           bb + sdst);
        gload_lds16(b + 64 * K,  bb + sdst + 4096);
        gload_lds16(b + 128 * K, bb + sdst + 8192);
        gload_lds16(b + 192 * K, bb + sdst + 12288);
    };
    auto READ = [&](const bf16* buf) {                     // 16 ds_read_b128
        const bf16* ba = buf;
        const bf16* bb = buf + A_ELE;
        #pragma unroll
        for (int mi = 0; mi < 2; mi++)
            #pragma unroll
            for (int kf = 0; kf < 4; kf++)
                av[mi][kf] = *reinterpret_cast<const bf16x8*>(ba + aoff + mi * 2048 + sl[kf]);
        #pragma unroll
        for (int ni = 0; ni < 2; ni++)
            #pragma unroll
            for (int kf = 0; kf < 4; kf++)
                bv[ni][kf] = *reinterpret_cast<const bf16x8*>(bb + boff + ni * 2048 + sl[kf]);
    };
    auto MFMA16 = [&]() {
        #pragma unroll
        for (int kf = 0; kf < 4; kf++)
            #pragma unroll
            for (int mi = 0; mi < 2; mi++)
                #pragma unroll
                for (int ni = 0; ni < 2; ni++)
                    acc[mi][ni] = __builtin_amdgcn_mfma_f32_32x32x16_bf16(av[mi][kf], bv[ni][kf], acc[mi][ni], 0, 0, 0);
    };
    auto TILE = [&](int t, int cb, int sb) {
        READ((const bf16*)lds + cb * BUF_ELE);
        STAGE(sb, t + 2);
        __builtin_amdgcn_s_setprio(1);
        MFMA16();
        __builtin_amdgcn_s_setprio(0);
        asm volatile("s_waitcnt lgkmcnt(0)" ::: "memory");
        asm volatile("s_waitcnt vmcnt(6)" ::: "memory");
        __builtin_amdgcn_s_barrier();
    };

    STAGE(0, 0);
    STAGE(1, 1);
    asm volatile("s_waitcnt vmcnt(6)" ::: "memory");
    __builtin_amdgcn_s_barrier();

    for (int i = 0; i < 10; ++i) {
        TILE(3 * i,     0, 2);
        TILE(3 * i + 1, 1, 0);
        TILE(3 * i + 2, 2, 1);
    }
    {
        READ((const bf16*)lds);
        MFMA16();
        asm volatile("s_waitcnt lgkmcnt(0)" ::: "memory");
        asm volatile("s_waitcnt vmcnt(0)" ::: "memory");
        __builtin_amdgcn_s_barrier();
    }
    {
        READ((const bf16*)lds + BUF_ELE);
        MFMA16();
    }

    // C/D layout (32x32): col = lane&31, row = (reg&3) + 8*(reg>>2) + 4*(lane>>5)
    int row0 = tm * BM + wr * 64 + 4 * hi;
    int col0 = tn * BN + wc * 64 + fr5;
    #pragma unroll
    for (int mi = 0; mi < 2; mi++)
        #pragma unroll
        for (int ni = 0; ni < 2; ni++)
            #pragma unroll
            for (int r = 0; r < 16; r++) {
                int row = row0 + mi * 32 + (r & 3) + 8 * (r >> 2);
                Cout[(size_t)row * N + col0 + ni * 32] = acc[mi][ni][r];
            }
}

extern "C" void kernel_launch(void* const* d_in, const int* in_sizes, int n_in,
                              void* d_out, int out_size, void* d_ws, size_t ws_size,
                              hipStream_t stream) {
    const float* x0 = (const float*)d_in[0];
    const float* x1 = (const float*)d_in[1];
    const float* W0 = (const float*)d_in[2];
    const float* W1 = (const float*)d_in[3];
    const float* W2 = (const float*)d_in[4];

    // out = X @ (W0@W1@W2)  [68.7 GFLOP]
    char* ws = (char*)d_ws;
    const size_t MB = 1024 * 1024;
    bf16* Xpk    = (bf16*)(ws + 0 * MB);
    bf16* W1t    = (bf16*)(ws + 16 * MB);
    bf16* W012t  = (bf16*)(ws + 16 * MB);    // overlays W1t (dead after G1)
    bf16* W2t    = (bf16*)(ws + 24 * MB);
    bf16* W01    = (bf16*)(ws + 32 * MB);
    bf16* W0pk   = (bf16*)d_out;             // dead before G3 writes

    k1_prep<<<2048 + 4096, 256, 0, stream>>>(W0, W0pk, W1, W1t);
    g1_fused<<<WGRID + 4096, 256, 0, stream>>>(W0pk, W1t, W01, W2, W2t);
    g2_fused<<<WGRID + 4096, 256, 0, stream>>>(W2t, W01, W012t, x0, x1, Xpk);
    gemmx_kernel<<<(M / BM) * (N / BN), 512, 0, stream>>>(Xpk, W012t, (float*)d_out);
}

// Round 14
// 106.513 us; speedup vs baseline: 1.0361x; 1.0361x over previous
//
#include <hip/hip_runtime.h>
#include <hip/hip_bf16.h>
#include <stdint.h>

typedef __bf16 bf16;
typedef __bf16 bf16x8 __attribute__((ext_vector_type(8)));
typedef float f32x4 __attribute__((ext_vector_type(4)));

#define GAS __attribute__((address_space(1)))
#define LAS __attribute__((address_space(3)))

static constexpr int M = 4096;   // batch
static constexpr int N = 2048;   // 2C
static constexpr int K = 2048;   // 2C

// ---- G3 geometry: 128x256, 8 waves (2M x 4N, 64x64/wave), 16x16x32 MFMA ----
static constexpr int BM = 128, BN = 256, BK = 64;
static constexpr int NT = K / BK;               // 32 K-tiles
static constexpr int A_ELE = BM * BK;           // 16 KB
static constexpr int B_ELE = BN * BK;           // 32 KB
static constexpr int BUF_ELE = A_ELE + B_ELE;   // 48 KB; x3 = 144 KB

// ---- G1/G2 geometry: 64x128, 4 waves, 2 blocks/CU ----
static constexpr int WA_ELE = 64 * BK;              // 8 KB
static constexpr int WB_ELE = 128 * BK;             // 16 KB
static constexpr int WBUF_ELE = WA_ELE + WB_ELE;    // 24 KB; x3 = 72 KB
static constexpr int WGRID = 512;

// --- async global->LDS, 16B per lane, dest = wave-uniform base + lane*16 ---
__device__ __forceinline__ void gload_lds16(const bf16* gsrc, bf16* ldst) {
    __builtin_amdgcn_global_load_lds((const GAS void*)gsrc, (LAS void*)ldst, 16, 0, 0);
}

// ---- pack 8 fp32 -> 8 bf16 ----
__device__ __forceinline__ void pack8(const float* __restrict__ src, bf16* __restrict__ dst) {
    float4 v0 = *reinterpret_cast<const float4*>(src);
    float4 v1 = *reinterpret_cast<const float4*>(src + 4);
    bf16x8 o;
    o[0] = (bf16)v0.x; o[1] = (bf16)v0.y; o[2] = (bf16)v0.z; o[3] = (bf16)v0.w;
    o[4] = (bf16)v1.x; o[5] = (bf16)v1.y; o[6] = (bf16)v1.z; o[7] = (bf16)v1.w;
    *reinterpret_cast<bf16x8*>(dst) = o;
}

__device__ __forceinline__ bf16x8 cvt2(float4 a, float4 b) {
    bf16x8 o;
    o[0] = (bf16)a.x; o[1] = (bf16)a.y; o[2] = (bf16)a.z; o[3] = (bf16)a.w;
    o[4] = (bf16)b.x; o[5] = (bf16)b.y; o[6] = (bf16)b.z; o[7] = (bf16)b.w;
    return o;
}

// ---- 32x32 LDS-tiled transpose: Wt[n][k] = (bf16)W[k][n] ----
__device__ __forceinline__ void transpose_tile(const float* __restrict__ W, bf16* __restrict__ Wt,
                                               int t, int tid, bf16 (*tile)[33]) {
    int n0 = (t & 63) * 32;
    int k0 = (t >> 6) * 32;
    int tx = tid & 31;
    int ty = tid >> 5;
    #pragma unroll
    for (int i = 0; i < 4; i++) {
        int k = ty + i * 8;
        tile[k][tx] = (bf16)W[(size_t)(k0 + k) * N + n0 + tx];
    }
    __syncthreads();
    #pragma unroll
    for (int i = 0; i < 4; i++) {
        int n = ty + i * 8;
        Wt[(size_t)(n0 + n) * K + k0 + tx] = tile[tx][n];
    }
}

// ===== K1: pack W0 ; transpose W1 ; transpose W2 =====
__global__ __launch_bounds__(256) void k1_prep(const float* __restrict__ W0, bf16* __restrict__ W0pk,
                                               const float* __restrict__ W1, bf16* __restrict__ W1t,
                                               const float* __restrict__ W2, bf16* __restrict__ W2t) {
    __shared__ bf16 tile[32][33];
    int bid = blockIdx.x;
    int tid = threadIdx.x;
    if (bid < 2048) {
        int idx = (bid * 256 + tid) * 8;
        pack8(W0 + idx, W0pk + idx);
    } else if (bid < 6144) {
        transpose_tile(W1, W1t, bid - 2048, tid, tile);
    } else {
        transpose_tile(W2, W2t, bid - 6144, tid, tile);
    }
}

// ================= weight GEMM body (64x128 tile, 4 waves, 16x16x32) =================
// XP: fuse X-pack into the pipeline. Each block packs 16384 elems of X (64/thread) in
// 4 helper rounds at tiles 3/6/9/12: 4 float4 loads issued BEFORE STAGE (queue order
// [stage(t+1)^6][h^4][stage(t+2)^6] so the standard mid vmcnt(6) drains stage(t+1)+h
// with no extra stall); cvt + 2 bf16x8 stores after; tile-after uses vmcnt(8) to leave
// the 2 stores in flight. Helper HBM (~1.6 TB/s) rides the GEMM's spare bandwidth.
template <bool XP>
__device__ __forceinline__ void gemmw_body(const bf16* __restrict__ A,
                                           const bf16* __restrict__ Bt,
                                           bf16* __restrict__ C,
                                           int bid, bf16* lds,
                                           const float* __restrict__ x0,
                                           const float* __restrict__ x1,
                                           bf16* __restrict__ Xpk) {
    int swz = (bid & 7) * (WGRID >> 3) + (bid >> 3);
    int tm = swz >> 4;
    int tn = swz & 15;

    int tid  = threadIdx.x;
    int wave = tid >> 6;
    int lane = tid & 63;
    int wr = wave >> 1;
    int wc = wave & 1;
    int fr = lane & 15;
    int fb = lane >> 4;

    int srow = tid >> 3;
    int scol = ((tid & 7) ^ (srow & 7)) * 8;
    const bf16* aS = A  + (size_t)(tm * 64  + srow) * K + scol;
    const bf16* bS = Bt + (size_t)(tn * 128 + srow) * K + scol;
    int sdst = wave * 512;

    int aoff  = (wr * 32 + fr) * 64;
    int boff  = (wc * 64 + fr) * 64;
    int slot0 = ((fb) ^ (fr & 7)) * 8;
    int slot1 = ((4 | fb) ^ (fr & 7)) * 8;

    // helper chunk: block covers elems [bid*16384, +16384); thread: 64 contiguous elems
    const float* hsrc = nullptr;
    bf16* hdst = nullptr;
    if constexpr (XP) {
        int chunk = bid * 16384 + tid * 64;           // 64-elem chunks never straddle the seam
        int r = chunk >> 11;
        int c = chunk & 2047;
        hsrc = (c < 1024) ? (x0 + (size_t)r * 1024 + c)
                          : (x1 + (size_t)r * 1024 + (c - 1024));
        hdst = Xpk + chunk;
    }

    f32x4 acc[2][4] = {};
    bf16x8 af0[2], bv0[4], af1[2], bv1[4];

    auto STAGE = [&](int bi, int t) {
        bf16* ba = lds + bi * WBUF_ELE;
        bf16* bb = ba + WA_ELE;
        const bf16* a = aS + t * BK;
        const bf16* b = bS + t * BK;
        gload_lds16(a,          ba + sdst);
        gload_lds16(a + 32 * K, ba + sdst + 2048);
        #pragma unroll
        for (int c = 0; c < 4; c++)
            gload_lds16(b + (size_t)c * 32 * K, bb + sdst + c * 2048);
    };
    auto READ = [&](const bf16* ba, const bf16* bb, int slot, bf16x8 af[2], bf16x8 bv[4]) {
        af[0] = *reinterpret_cast<const bf16x8*>(ba + aoff + slot);
        af[1] = *reinterpret_cast<const bf16x8*>(ba + aoff + 1024 + slot);
        #pragma unroll
        for (int ni = 0; ni < 4; ni++)
            bv[ni] = *reinterpret_cast<const bf16x8*>(bb + boff + ni * 1024 + slot);
    };
    auto MFMA8 = [&](const bf16x8 af[2], const bf16x8 bv[4]) {
        #pragma unroll
        for (int mi = 0; mi < 2; mi++)
            #pragma unroll
            for (int ni = 0; ni < 4; ni++)
                acc[mi][ni] = __builtin_amdgcn_mfma_f32_16x16x32_bf16(af[mi], bv[ni], acc[mi][ni], 0, 0, 0);
    };

    // hr: helper round (-1 none); vm8: use vmcnt(8) at tile end (tile after a helper tile)
    auto TILE = [&](int t, int cb, int sb, int hr, bool vm8) {
        const bf16* ba = lds + cb * WBUF_ELE;
        const bf16* bb = ba + WA_ELE;
        READ(ba, bb, slot0, af0, bv0);
        READ(ba, bb, slot1, af1, bv1);
        float4 h0, h1, h2, h3;
        if (XP && hr >= 0) {                               // BEFORE stage: queue [st(t+1)][h][st(t+2)]
            const float* p = hsrc + hr * 16;
            h0 = *reinterpret_cast<const float4*>(p);
            h1 = *reinterpret_cast<const float4*>(p + 4);
            h2 = *reinterpret_cast<const float4*>(p + 8);
            h3 = *reinterpret_cast<const float4*>(p + 12);
        }
        STAGE(sb, t + 2);
        __builtin_amdgcn_s_setprio(1);
        MFMA8(af0, bv0);
        MFMA8(af1, bv1);
        __builtin_amdgcn_s_setprio(0);
        asm volatile("s_waitcnt lgkmcnt(0)" ::: "memory");
        if (XP && hr >= 0) {
            asm volatile("s_waitcnt vmcnt(6)" ::: "memory");   // drains stage(t+1) AND hloads
            bf16* q = hdst + hr * 16;
            *reinterpret_cast<bf16x8*>(q)     = cvt2(h0, h1);
            *reinterpret_cast<bf16x8*>(q + 8) = cvt2(h2, h3);
        } else if (XP && vm8) {
            asm volatile("s_waitcnt vmcnt(8)" ::: "memory");   // leaves stage(t+2)+2 hstores
        } else {
            asm volatile("s_waitcnt vmcnt(6)" ::: "memory");
        }
        __builtin_amdgcn_s_barrier();
    };

    STAGE(0, 0);
    STAGE(1, 1);
    asm volatile("s_waitcnt vmcnt(6)" ::: "memory");
    __builtin_amdgcn_s_barrier();

    // t = 0..2
    TILE(0, 0, 2, -1, false);
    TILE(1, 1, 0, -1, false);
    TILE(2, 2, 1, -1, false);
    // t = 3..14: helper rounds 0..3 at t = 3,6,9,12
    for (int i = 1; i <= 4; ++i) {
        TILE(3 * i,     0, 2, i - 1, false);
        TILE(3 * i + 1, 1, 0, -1,    true);
        TILE(3 * i + 2, 2, 1, -1,    false);
    }
    // t = 15..29
    for (int i = 5; i < 10; ++i) {
        TILE(3 * i,     0, 2, -1, false);
        TILE(3 * i + 1, 1, 0, -1, false);
        TILE(3 * i + 2, 2, 1, -1, false);
    }
    {   // t = 30 (buf0): no staging; drain all
        const bf16* ba = lds;
        const bf16* bb = ba + WA_ELE;
        READ(ba, bb, slot0, af0, bv0);
        READ(ba, bb, slot1, af1, bv1);
        MFMA8(af0, bv0);
        MFMA8(af1, bv1);
        asm volatile("s_waitcnt lgkmcnt(0)" ::: "memory");
        asm volatile("s_waitcnt vmcnt(0)" ::: "memory");
        __builtin_amdgcn_s_barrier();
    }
    {   // t = 31 (buf1)
        const bf16* ba = lds + WBUF_ELE;
        const bf16* bb = ba + WA_ELE;
        READ(ba, bb, slot0, af0, bv0);
        READ(ba, bb, slot1, af1, bv1);
        MFMA8(af0, bv0);
        MFMA8(af1, bv1);
    }

    int row0 = tm * 64 + wr * 32 + (lane >> 4) * 4;
    int col0 = tn * 128 + wc * 64 + fr;
    #pragma unroll
    for (int mi = 0; mi < 2; mi++)
        #pragma unroll
        for (int r = 0; r < 4; r++) {
            size_t base = (size_t)(row0 + mi * 16 + r) * 2048 + col0;
            #pragma unroll
            for (int ni = 0; ni < 4; ni++)
                C[base + ni * 16] = (bf16)acc[mi][ni][r];
        }
}

// ===== G1: W01 = W0 @ W1  (+ fused X-pack riding the pipeline) =====
__global__ __launch_bounds__(256, 2) void gw1_kernel(const bf16* __restrict__ A, const bf16* __restrict__ Bt,
                                                     bf16* __restrict__ C,
                                                     const float* __restrict__ x0, const float* __restrict__ x1,
                                                     bf16* __restrict__ Xpk) {
    __shared__ bf16 lds[3 * WBUF_ELE];
    gemmw_body<true>(A, Bt, C, blockIdx.x, lds, x0, x1, Xpk);
}

// ===== G2: W012t = W2t @ W01^T (pure) =====
__global__ __launch_bounds__(256, 2) void gw2_kernel(const bf16* __restrict__ A, const bf16* __restrict__ Bt,
                                                     bf16* __restrict__ C) {
    __shared__ bf16 lds[3 * WBUF_ELE];
    gemmw_body<false>(A, Bt, C, blockIdx.x, lds, nullptr, nullptr, nullptr);
}

// ========== K4: G3 = Xpk @ W012t^T (128x256, 8 waves, 16x16x32 — R8 exact) ==========
__global__ __launch_bounds__(512, 2) void gemmx_kernel(const bf16* __restrict__ A,   // [4096][K]
                                                       const bf16* __restrict__ Bt,  // [N][K]
                                                       float* __restrict__ Cout) {   // [4096][N] fp32
    __shared__ bf16 lds[3 * BUF_ELE];   // 144 KB

    int bid = blockIdx.x;
    int cpx = gridDim.x >> 3;
    int swz = (bid & 7) * cpx + (bid >> 3);
    int tm = swz >> 3;                           // 0..31
    int tn = swz & 7;                            // 0..7

    int tid  = threadIdx.x;
    int wave = tid >> 6;
    int lane = tid & 63;
    int wr = wave >> 2;
    int wc = wave & 3;
    int fr = lane & 15;
    int fb = lane >> 4;

    int srow = wave * 8 + (lane >> 3);
    int scol = ((lane & 7) ^ (lane >> 3)) * 8;
    const bf16* aS = A  + (size_t)(tm * BM + srow) * K + scol;
    const bf16* bS = Bt + (size_t)(tn * BN + srow) * K + scol;
    int sdst = wave * 512;

    int aoff  = (wr * 64 + fr) * 64;
    int boff  = (wc * 64 + fr) * 64;
    int slot0 = ((fb) ^ (fr & 7)) * 8;
    int slot1 = ((4 | fb) ^ (fr & 7)) * 8;

    f32x4 acc[4][4] = {};
    bf16x8 af0[4], bv0[4], af1[4], bv1[4];

    auto STAGE = [&](int bi, int t) {
        bf16* ba = (bf16*)lds + bi * BUF_ELE;
        bf16* bb = ba + A_ELE;
        const bf16* a = aS + t * BK;
        const bf16* b = bS + t * BK;
        gload_lds16(a,           ba + sdst);
        gload_lds16(a + 64 * K,  ba + sdst + 4096);
        gload_lds16(b,           bb + sdst);
        gload_lds16(b + 64 * K,  bb + sdst + 4096);
        gload_lds16(b + 128 * K, bb + sdst + 8192);
        gload_lds16(b + 192 * K, bb + sdst + 12288);
    };
    auto READ = [&](const bf16* ba, const bf16* bb, int slot, bf16x8 af[4], bf16x8 bv[4]) {
        #pragma unroll
        for (int mi = 0; mi < 4; mi++)
            af[mi] = *reinterpret_cast<const bf16x8*>(ba + aoff + mi * 1024 + slot);
        #pragma unroll
        for (int ni = 0; ni < 4; ni++)
            bv[ni] = *reinterpret_cast<const bf16x8*>(bb + boff + ni * 1024 + slot);
    };
    auto MFMA16 = [&](const bf16x8 af[4], const bf16x8 bv[4]) {
        #pragma unroll
        for (int mi = 0; mi < 4; mi++)
            #pragma unroll
            for (int ni = 0; ni < 4; ni++)
                acc[mi][ni] = __builtin_amdgcn_mfma_f32_16x16x32_bf16(af[mi], bv[ni], acc[mi][ni], 0, 0, 0);
    };
    auto TILE = [&](int t, int cb, int sb) {
        const bf16* ba = (const bf16*)lds + cb * BUF_ELE;
        const bf16* bb = ba + A_ELE;
        READ(ba, bb, slot0, af0, bv0);
        READ(ba, bb, slot1, af1, bv1);
        STAGE(sb, t + 2);
        __builtin_amdgcn_s_setprio(1);
        MFMA16(af0, bv0);
        MFMA16(af1, bv1);
        __builtin_amdgcn_s_setprio(0);
        asm volatile("s_waitcnt lgkmcnt(0)" ::: "memory");
        asm volatile("s_waitcnt vmcnt(6)" ::: "memory");
        __builtin_amdgcn_s_barrier();
    };

    STAGE(0, 0);
    STAGE(1, 1);
    asm volatile("s_waitcnt vmcnt(6)" ::: "memory");
    __builtin_amdgcn_s_barrier();

    for (int i = 0; i < 10; ++i) {
        TILE(3 * i,     0, 2);
        TILE(3 * i + 1, 1, 0);
        TILE(3 * i + 2, 2, 1);
    }
    {
        const bf16* ba = (const bf16*)lds;
        const bf16* bb = ba + A_ELE;
        READ(ba, bb, slot0, af0, bv0);
        READ(ba, bb, slot1, af1, bv1);
        MFMA16(af0, bv0);
        MFMA16(af1, bv1);
        asm volatile("s_waitcnt lgkmcnt(0)" ::: "memory");
        asm volatile("s_waitcnt vmcnt(0)" ::: "memory");
        __builtin_amdgcn_s_barrier();
    }
    {
        const bf16* ba = (const bf16*)lds + BUF_ELE;
        const bf16* bb = ba + A_ELE;
        READ(ba, bb, slot0, af0, bv0);
        READ(ba, bb, slot1, af1, bv1);
        MFMA16(af0, bv0);
        MFMA16(af1, bv1);
    }

    int row0 = tm * BM + wr * 64 + (lane >> 4) * 4;
    int col0 = tn * BN + wc * 64 + (lane & 15);
    #pragma unroll
    for (int mi = 0; mi < 4; mi++)
        #pragma unroll
        for (int r = 0; r < 4; r++) {
            size_t base = (size_t)(row0 + mi * 16 + r) * N + col0;
            #pragma unroll
            for (int ni = 0; ni < 4; ni++)
                Cout[base + ni * 16] = acc[mi][ni][r];
        }
}

extern "C" void kernel_launch(void* const* d_in, const int* in_sizes, int n_in,
                              void* d_out, int out_size, void* d_ws, size_t ws_size,
                              hipStream_t stream) {
    const float* x0 = (const float*)d_in[0];
    const float* x1 = (const float*)d_in[1];
    const float* W0 = (const float*)d_in[2];
    const float* W1 = (const float*)d_in[3];
    const float* W2 = (const float*)d_in[4];

    // out = X @ (W0@W1@W2)  [68.7 GFLOP]
    // ws (40 MB): Xpk@0 (16M), W1t@16M (overlaid by W012t after G1), W2t@24M, W01@32M.
    // W0pk lives in d_out (dead before G3 writes).
    char* ws = (char*)d_ws;
    const size_t MB = 1024 * 1024;
    bf16* Xpk    = (bf16*)(ws + 0 * MB);
    bf16* W1t    = (bf16*)(ws + 16 * MB);
    bf16* W012t  = (bf16*)(ws + 16 * MB);    // overlays W1t (dead after G1)
    bf16* W2t    = (bf16*)(ws + 24 * MB);
    bf16* W01    = (bf16*)(ws + 32 * MB);
    bf16* W0pk   = (bf16*)d_out;             // dead before G3 writes

    // K1: pack W0, transpose W1, transpose W2 (full-BW, no LDS starvation)
    k1_prep<<<2048 + 4096 + 4096, 256, 0, stream>>>(W0, W0pk, W1, W1t, W2, W2t);
    // G1: W01 = W0 @ W1  (+ X-pack fused INTO the pipeline — true overlap)
    gw1_kernel<<<WGRID, 256, 0, stream>>>(W0pk, W1t, W01, x0, x1, Xpk);
    // G2: W012t = (W01@W2)^T = W2t @ W01^T
    gw2_kernel<<<WGRID, 256, 0, stream>>>(W2t, W01, W012t);
    // G3: out = X @ W012
    gemmx_kernel<<<(M / BM) * (N / BN), 512, 0, stream>>>(Xpk, W012t, (float*)d_out);
}

// Round 15
// 100.017 us; speedup vs baseline: 1.1034x; 1.0650x over previous
//
#include <hip/hip_runtime.h>
#include <hip/hip_bf16.h>
#include <stdint.h>

typedef __bf16 bf16;
typedef __bf16 bf16x8 __attribute__((ext_vector_type(8)));
typedef float f32x4 __attribute__((ext_vector_type(4)));

#define GAS __attribute__((address_space(1)))
#define LAS __attribute__((address_space(3)))

static constexpr int M = 4096;   // batch
static constexpr int N = 2048;   // 2C
static constexpr int K = 2048;   // 2C

// ---- G3 geometry: 128x256, 8 waves (2M x 4N, 64x64/wave), cross-tile pipelined ----
static constexpr int BM = 128, BN = 256, BK = 64;
static constexpr int NT = K / BK;               // 32 K-tiles
static constexpr int A_ELE = BM * BK;           // 16 KB
static constexpr int B_ELE = BN * BK;           // 32 KB
static constexpr int BUF_ELE = A_ELE + B_ELE;   // 48 KB; x3 = 144 KB

// ---- G1/G2 geometry: 64x128, 4 waves, 2 blocks/CU ----
static constexpr int WA_ELE = 64 * BK;              // 8 KB
static constexpr int WB_ELE = 128 * BK;             // 16 KB
static constexpr int WBUF_ELE = WA_ELE + WB_ELE;    // 24 KB; x3 = 72 KB
static constexpr int WGRID = 512;

// --- async global->LDS, 16B per lane, dest = wave-uniform base + lane*16 ---
__device__ __forceinline__ void gload_lds16(const bf16* gsrc, bf16* ldst) {
    __builtin_amdgcn_global_load_lds((const GAS void*)gsrc, (LAS void*)ldst, 16, 0, 0);
}

// ---- pack 8 fp32 -> 8 bf16 ----
__device__ __forceinline__ void pack8(const float* __restrict__ src, bf16* __restrict__ dst) {
    float4 v0 = *reinterpret_cast<const float4*>(src);
    float4 v1 = *reinterpret_cast<const float4*>(src + 4);
    bf16x8 o;
    o[0] = (bf16)v0.x; o[1] = (bf16)v0.y; o[2] = (bf16)v0.z; o[3] = (bf16)v0.w;
    o[4] = (bf16)v1.x; o[5] = (bf16)v1.y; o[6] = (bf16)v1.z; o[7] = (bf16)v1.w;
    *reinterpret_cast<bf16x8*>(dst) = o;
}

// ---- 32x32 LDS-tiled transpose: Wt[n][k] = (bf16)W[k][n] ----
__device__ __forceinline__ void transpose_tile(const float* __restrict__ W, bf16* __restrict__ Wt,
                                               int t, int tid, bf16 (*tile)[33]) {
    int n0 = (t & 63) * 32;
    int k0 = (t >> 6) * 32;
    int tx = tid & 31;
    int ty = tid >> 5;
    #pragma unroll
    for (int i = 0; i < 4; i++) {
        int k = ty + i * 8;
        tile[k][tx] = (bf16)W[(size_t)(k0 + k) * N + n0 + tx];
    }
    __syncthreads();
    #pragma unroll
    for (int i = 0; i < 4; i++) {
        int n = ty + i * 8;
        Wt[(size_t)(n0 + n) * K + k0 + tx] = tile[tx][n];
    }
}

// ================= weight GEMM body (64x128 tile, 4 waves, 2 blk/CU) =================
__device__ __forceinline__ void gemmw_body(const bf16* __restrict__ A,
                                           const bf16* __restrict__ Bt,
                                           bf16* __restrict__ C,
                                           int bid, bf16* lds) {
    int swz = (bid & 7) * (WGRID >> 3) + (bid >> 3);
    int tm = swz >> 4;
    int tn = swz & 15;

    int tid  = threadIdx.x;
    int wave = tid >> 6;
    int lane = tid & 63;
    int wr = wave >> 1;
    int wc = wave & 1;
    int fr = lane & 15;
    int fb = lane >> 4;

    int srow = tid >> 3;
    int scol = ((tid & 7) ^ (srow & 7)) * 8;
    const bf16* aS = A  + (size_t)(tm * 64  + srow) * K + scol;
    const bf16* bS = Bt + (size_t)(tn * 128 + srow) * K + scol;
    int sdst = wave * 512;

    int aoff  = (wr * 32 + fr) * 64;
    int boff  = (wc * 64 + fr) * 64;
    int slot0 = ((fb) ^ (fr & 7)) * 8;
    int slot1 = ((4 | fb) ^ (fr & 7)) * 8;

    f32x4 acc[2][4] = {};
    bf16x8 af0[2], bv0[4], af1[2], bv1[4];

    auto STAGE = [&](int bi, int t) {
        bf16* ba = lds + bi * WBUF_ELE;
        bf16* bb = ba + WA_ELE;
        const bf16* a = aS + t * BK;
        const bf16* b = bS + t * BK;
        gload_lds16(a,          ba + sdst);
        gload_lds16(a + 32 * K, ba + sdst + 2048);
        #pragma unroll
        for (int c = 0; c < 4; c++)
            gload_lds16(b + (size_t)c * 32 * K, bb + sdst + c * 2048);
    };
    auto READ = [&](const bf16* ba, const bf16* bb, int slot, bf16x8 af[2], bf16x8 bv[4]) {
        af[0] = *reinterpret_cast<const bf16x8*>(ba + aoff + slot);
        af[1] = *reinterpret_cast<const bf16x8*>(ba + aoff + 1024 + slot);
        #pragma unroll
        for (int ni = 0; ni < 4; ni++)
            bv[ni] = *reinterpret_cast<const bf16x8*>(bb + boff + ni * 1024 + slot);
    };
    auto MFMA8 = [&](const bf16x8 af[2], const bf16x8 bv[4]) {
        #pragma unroll
        for (int mi = 0; mi < 2; mi++)
            #pragma unroll
            for (int ni = 0; ni < 4; ni++)
                acc[mi][ni] = __builtin_amdgcn_mfma_f32_16x16x32_bf16(af[mi], bv[ni], acc[mi][ni], 0, 0, 0);
    };
    auto TILE = [&](int t, int cb, int sb) {
        const bf16* ba = lds + cb * WBUF_ELE;
        const bf16* bb = ba + WA_ELE;
        READ(ba, bb, slot0, af0, bv0);
        READ(ba, bb, slot1, af1, bv1);
        STAGE(sb, t + 2);
        __builtin_amdgcn_s_setprio(1);
        MFMA8(af0, bv0);
        MFMA8(af1, bv1);
        __builtin_amdgcn_s_setprio(0);
        asm volatile("s_waitcnt lgkmcnt(0)" ::: "memory");
        asm volatile("s_waitcnt vmcnt(6)" ::: "memory");
        __builtin_amdgcn_s_barrier();
    };

    STAGE(0, 0);
    STAGE(1, 1);
    asm volatile("s_waitcnt vmcnt(6)" ::: "memory");
    __builtin_amdgcn_s_barrier();

    for (int i = 0; i < 10; ++i) {
        TILE(3 * i,     0, 2);
        TILE(3 * i + 1, 1, 0);
        TILE(3 * i + 2, 2, 1);
    }
    {
        const bf16* ba = lds;
        const bf16* bb = ba + WA_ELE;
        READ(ba, bb, slot0, af0, bv0);
        READ(ba, bb, slot1, af1, bv1);
        MFMA8(af0, bv0);
        MFMA8(af1, bv1);
        asm volatile("s_waitcnt lgkmcnt(0)" ::: "memory");
        asm volatile("s_waitcnt vmcnt(0)" ::: "memory");
        __builtin_amdgcn_s_barrier();
    }
    {
        const bf16* ba = lds + WBUF_ELE;
        const bf16* bb = ba + WA_ELE;
        READ(ba, bb, slot0, af0, bv0);
        READ(ba, bb, slot1, af1, bv1);
        MFMA8(af0, bv0);
        MFMA8(af1, bv1);
    }

    int row0 = tm * 64 + wr * 32 + (lane >> 4) * 4;
    int col0 = tn * 128 + wc * 64 + fr;
    #pragma unroll
    for (int mi = 0; mi < 2; mi++)
        #pragma unroll
        for (int r = 0; r < 4; r++) {
            size_t base = (size_t)(row0 + mi * 16 + r) * 2048 + col0;
            #pragma unroll
            for (int ni = 0; ni < 4; ni++)
                C[base + ni * 16] = (bf16)acc[mi][ni][r];
        }
}

// ===== K1: pack W0 ; transpose W1 =====
__global__ __launch_bounds__(256) void k1_prep(const float* __restrict__ W0, bf16* __restrict__ W0pk,
                                               const float* __restrict__ W1, bf16* __restrict__ W1t) {
    __shared__ bf16 tile[32][33];
    int bid = blockIdx.x;
    int tid = threadIdx.x;
    if (bid < 2048) {
        int idx = (bid * 256 + tid) * 8;
        pack8(W0 + idx, W0pk + idx);
    } else {
        transpose_tile(W1, W1t, bid - 2048, tid, tile);
    }
}

// ===== K2: G1 || transpose W2 =====
__global__ __launch_bounds__(256, 2) void g1_fused(const bf16* __restrict__ A, const bf16* __restrict__ Bt,
                                                   bf16* __restrict__ C,
                                                   const float* __restrict__ W2, bf16* __restrict__ W2t) {
    __shared__ bf16 lds[3 * WBUF_ELE];
    int bid = blockIdx.x;
    if (bid < WGRID) {
        gemmw_body(A, Bt, C, bid, lds);
    } else {
        transpose_tile(W2, W2t, bid - WGRID, threadIdx.x, (bf16(*)[33])lds);
    }
}

// ===== K3: G2 || pack X =====
__global__ __launch_bounds__(256, 2) void g2_fused(const bf16* __restrict__ A, const bf16* __restrict__ Bt,
                                                   bf16* __restrict__ C,
                                                   const float* __restrict__ x0, const float* __restrict__ x1,
                                                   bf16* __restrict__ Xpk) {
    __shared__ bf16 lds[3 * WBUF_ELE];
    int bid = blockIdx.x;
    if (bid < WGRID) {
        gemmw_body(A, Bt, C, bid, lds);
    } else {
        int idx = ((bid - WGRID) * 256 + threadIdx.x) * 8;
        int b = idx >> 11;
        int c = idx & 2047;
        const float* src = (c < 1024) ? (x0 + (size_t)b * 1024 + c)
                                      : (x1 + (size_t)b * 1024 + (c - 1024));
        pack8(src, Xpk + idx);
    }
}

// ========== K4: G3 — cross-tile register pipeline (R11, best measured) ==========
// During tile t: MFMA on bank(t&1) fragments (pre-read last tile) || issue 16 ds_read for
// tile t+1 into the other bank || STAGE(t+3) into buf[t%3] (depth-3).
// Residency: end-of-tile vmcnt(6) drains tile t+2 exactly when buf[t+2] is first read (t+1).
struct Frags { bf16x8 a0[4], a1[4], b0[4], b1[4]; };

__global__ __launch_bounds__(512, 2) void gemmx_kernel(const bf16* __restrict__ A,   // [4096][K]
                                                       const bf16* __restrict__ Bt,  // [N][K]
                                                       float* __restrict__ Cout) {   // [4096][N] fp32
    __shared__ bf16 lds[3 * BUF_ELE];   // 144 KB
    bf16* B0 = (bf16*)lds;
    bf16* B1 = B0 + BUF_ELE;
    bf16* B2 = B1 + BUF_ELE;

    int bid = blockIdx.x;
    int cpx = gridDim.x >> 3;
    int swz = (bid & 7) * cpx + (bid >> 3);
    int tm = swz >> 3;                           // 0..31
    int tn = swz & 7;                            // 0..7

    int tid  = threadIdx.x;
    int wave = tid >> 6;
    int lane = tid & 63;
    int wr = wave >> 2;
    int wc = wave & 3;
    int fr = lane & 15;
    int fb = lane >> 4;

    int srow = wave * 8 + (lane >> 3);
    int scol = ((lane & 7) ^ (lane >> 3)) * 8;            // T2 pre-swizzle
    const bf16* aS = A  + (size_t)(tm * BM + srow) * K + scol;
    const bf16* bS = Bt + (size_t)(tn * BN + srow) * K + scol;
    int sdst = wave * 512;

    int aoff  = (wr * 64 + fr) * 64;
    int boff  = (wc * 64 + fr) * 64;
    int slot0 = ((fb) ^ (fr & 7)) * 8;
    int slot1 = ((4 | fb) ^ (fr & 7)) * 8;

    f32x4 acc[4][4] = {};
    Frags fA, fB;                                          // static banks (rule #20)

    auto STAGE = [&](bf16* buf, int t) {                   // 6 gloads
        bf16* ba = buf;
        bf16* bb = buf + A_ELE;
        const bf16* a = aS + t * BK;
        const bf16* b = bS + t * BK;
        gload_lds16(a,           ba + sdst);
        gload_lds16(a + 64 * K,  ba + sdst + 4096);
        gload_lds16(b,           bb + sdst);
        gload_lds16(b + 64 * K,  bb + sdst + 4096);
        gload_lds16(b + 128 * K, bb + sdst + 8192);
        gload_lds16(b + 192 * K, bb + sdst + 12288);
    };
    auto READS = [&](const bf16* buf, Frags& f) {          // 16 ds_read_b128
        const bf16* ba = buf;
        const bf16* bb = buf + A_ELE;
        #pragma unroll
        for (int mi = 0; mi < 4; mi++) {
            f.a0[mi] = *reinterpret_cast<const bf16x8*>(ba + aoff + mi * 1024 + slot0);
            f.a1[mi] = *reinterpret_cast<const bf16x8*>(ba + aoff + mi * 1024 + slot1);
        }
        #pragma unroll
        for (int ni = 0; ni < 4; ni++) {
            f.b0[ni] = *reinterpret_cast<const bf16x8*>(bb + boff + ni * 1024 + slot0);
            f.b1[ni] = *reinterpret_cast<const bf16x8*>(bb + boff + ni * 1024 + slot1);
        }
    };
    auto MFMA32 = [&](const Frags& f) {
        __builtin_amdgcn_s_setprio(1);
        #pragma unroll
        for (int mi = 0; mi < 4; mi++)
            #pragma unroll
            for (int ni = 0; ni < 4; ni++)
                acc[mi][ni] = __builtin_amdgcn_mfma_f32_16x16x32_bf16(f.a0[mi], f.b0[ni], acc[mi][ni], 0, 0, 0);
        #pragma unroll
        for (int mi = 0; mi < 4; mi++)
            #pragma unroll
            for (int ni = 0; ni < 4; ni++)
                acc[mi][ni] = __builtin_amdgcn_mfma_f32_16x16x32_bf16(f.a1[mi], f.b1[ni], acc[mi][ni], 0, 0, 0);
        __builtin_amdgcn_s_setprio(0);
    };
    auto SYNC6 = [&]() {
        asm volatile("s_waitcnt lgkmcnt(0)" ::: "memory");
        asm volatile("s_waitcnt vmcnt(6)" ::: "memory");
        __builtin_amdgcn_s_barrier();
    };
    auto TILE_A = [&](bf16* bufR, bf16* bufS, int ts) {    // MFMA bank A, read into bank B
        READS(bufR, fB);
        __builtin_amdgcn_sched_barrier(0);
        STAGE(bufS, ts);
        __builtin_amdgcn_sched_barrier(0);
        MFMA32(fA);
        SYNC6();
    };
    auto TILE_B = [&](bf16* bufR, bf16* bufS, int ts) {    // MFMA bank B, read into bank A
        READS(bufR, fA);
        __builtin_amdgcn_sched_barrier(0);
        STAGE(bufS, ts);
        __builtin_amdgcn_sched_barrier(0);
        MFMA32(fB);
        SYNC6();
    };

    // ---- prologue: depth-3 staging; tiles 0,1 resident after barrier ----
    STAGE(B0, 0);
    STAGE(B1, 1);
    STAGE(B2, 2);
    asm volatile("s_waitcnt vmcnt(6)" ::: "memory");
    __builtin_amdgcn_s_barrier();
    READS(B0, fA);                                         // pre-read tile 0

    // ---- main loop: t = 0..23 (6-unrolled: buf period 3 x bank period 2) ----
    for (int i = 0; i < 4; ++i) {
        int t = 6 * i;
        TILE_A(B1, B0, t + 3);
        TILE_B(B2, B1, t + 4);
        TILE_A(B0, B2, t + 5);
        TILE_B(B1, B0, t + 6);
        TILE_A(B2, B1, t + 7);
        TILE_B(B0, B2, t + 8);
    }
    // ---- t = 24..28 (stage tiles 27..31) ----
    TILE_A(B1, B0, 27);
    TILE_B(B2, B1, 28);
    TILE_A(B0, B2, 29);
    TILE_B(B1, B0, 30);
    TILE_A(B2, B1, 31);
    // ---- t = 29: read tile 30, no staging, drain all loads ----
    {
        READS(B0, fA);
        __builtin_amdgcn_sched_barrier(0);
        MFMA32(fB);
        asm volatile("s_waitcnt lgkmcnt(0)" ::: "memory");
        asm volatile("s_waitcnt vmcnt(0)" ::: "memory");
        __builtin_amdgcn_s_barrier();
    }
    // ---- t = 30: read tile 31 ----
    {
        READS(B1, fB);
        __builtin_amdgcn_sched_barrier(0);
        MFMA32(fA);
    }
    // ---- t = 31 ----
    MFMA32(fB);

    // ---- epilogue: C/D layout col = lane&15, row = (lane>>4)*4 + reg ----
    int row0 = tm * BM + wr * 64 + (lane >> 4) * 4;
    int col0 = tn * BN + wc * 64 + (lane & 15);
    #pragma unroll
    for (int mi = 0; mi < 4; mi++)
        #pragma unroll
        for (int r = 0; r < 4; r++) {
            size_t base = (size_t)(row0 + mi * 16 + r) * N + col0;
            #pragma unroll
            for (int ni = 0; ni < 4; ni++)
                Cout[base + ni * 16] = acc[mi][ni][r];
        }
}

extern "C" void kernel_launch(void* const* d_in, const int* in_sizes, int n_in,
                              void* d_out, int out_size, void* d_ws, size_t ws_size,
                              hipStream_t stream) {
    const float* x0 = (const float*)d_in[0];
    const float* x1 = (const float*)d_in[1];
    const float* W0 = (const float*)d_in[2];
    const float* W1 = (const float*)d_in[3];
    const float* W2 = (const float*)d_in[4];

    // out = X @ (W0@W1@W2)  [68.7 GFLOP]
    char* ws = (char*)d_ws;
    const size_t MB = 1024 * 1024;
    bf16* Xpk    = (bf16*)(ws + 0 * MB);
    bf16* W1t    = (bf16*)(ws + 16 * MB);
    bf16* W012t  = (bf16*)(ws + 16 * MB);    // overlays W1t (dead after G1)
    bf16* W2t    = (bf16*)(ws + 24 * MB);
    bf16* W01    = (bf16*)(ws + 32 * MB);
    bf16* W0pk   = (bf16*)d_out;             // dead before G3 writes

    k1_prep<<<2048 + 4096, 256, 0, stream>>>(W0, W0pk, W1, W1t);
    g1_fused<<<WGRID + 4096, 256, 0, stream>>>(W0pk, W1t, W01, W2, W2t);
    g2_fused<<<WGRID + 4096, 256, 0, stream>>>(W2t, W01, W012t, x0, x1, Xpk);
    gemmx_kernel<<<(M / BM) * (N / BN), 512, 0, stream>>>(Xpk, W012t, (float*)d_out);
}